// Round 10
// baseline (199.144 us; speedup 1.0000x reference)
//
#include <hip/hip_runtime.h>

// GraphSAGE forward: 2x SAGEConv(mean) + ReLU, then link scorer. D = H = 256.
// Bucket-slot edge lists (no scan) -> wide-parallel gather-mean -> MFMA GEMM.
// R9 structure; only change: gemm row-split deepened to 128 rows/block
// (8 waves share the same 4 col-tiles) -> B L2-traffic 160->80 MB/layer.

#define DIM 256
#define CAP 64   // max degree capacity per node (Poisson(10): P(>64) ~ 1e-31)
typedef __attribute__((ext_vector_type(8))) short short8v;
typedef __attribute__((ext_vector_type(4))) float f32x4;

__device__ inline unsigned short f2b(float f) {
    unsigned u = __builtin_bit_cast(unsigned, f);
    unsigned r = 0x7FFFu + ((u >> 16) & 1u);
    return (unsigned short)((u + r) >> 16);
}
__device__ inline float b2f(unsigned short h) {
    unsigned u = ((unsigned)h) << 16;
    return __builtin_bit_cast(float, u);
}

// Pack 256x256 f32 row-major weights into bf16 MFMA B-fragment order, and zero
// the degree-count arrays (no separate memset dispatch).
// P[((nt*8+kt)*64+lane)*8+j] = bf16(W[kt*32 + 8*(lane>>4)+j][nt*16 + (lane&15)])
__global__ __launch_bounds__(64) void pack_zero(const float* __restrict__ W0, const float* __restrict__ W1,
                                                const float* __restrict__ W2, const float* __restrict__ W3,
                                                unsigned short* __restrict__ P0, unsigned short* __restrict__ P1,
                                                unsigned short* __restrict__ P2, unsigned short* __restrict__ P3,
                                                int* __restrict__ cntz, int nz) {
    const float* W; unsigned short* P;
    switch (blockIdx.z) {
        case 0: W = W0; P = P0; break;
        case 1: W = W1; P = P1; break;
        case 2: W = W2; P = P2; break;
        default: W = W3; P = P3; break;
    }
    int nt = blockIdx.x, kt = blockIdx.y, lane = threadIdx.x;
    int r = kt * 32 + ((lane >> 4) * 8);
    int c = nt * 16 + (lane & 15);
    short8v v;
    #pragma unroll
    for (int j = 0; j < 8; ++j) v[j] = f2b(W[(size_t)(r + j) * 256 + c]);
    *(short8v*)(P + ((size_t)(nt * 8 + kt) * 64 + lane) * 8) = v;
    int tid = ((blockIdx.z * gridDim.y + blockIdx.y) * gridDim.x + blockIdx.x) * 64 + lane;
    for (int i = tid; i < nz; i += 32768) cntz[i] = 0;
}

// inv scatter + bucket-slot scatter for both layers (cnt arrays pre-zeroed).
__global__ __launch_bounds__(256) void scatter_all(const int* __restrict__ n_id, int* __restrict__ inv, int n0,
                                                   const int* __restrict__ src1, const int* __restrict__ dst1, int E1,
                                                   int* __restrict__ cnt1, int* __restrict__ eidx1,
                                                   const int* __restrict__ src2, const int* __restrict__ dst2, int E2,
                                                   int* __restrict__ cnt2, int* __restrict__ eidx2) {
    int i = blockIdx.x * blockDim.x + threadIdx.x;
    if (i < n0) inv[n_id[i]] = i;
    if (i < E1) {
        int d = dst1[i];
        int s = atomicAdd(&cnt1[d], 1);
        if (s < CAP) eidx1[(size_t)d * CAP + s] = src1[i];
    }
    if (i < E2) {
        int d = dst2[i];
        int s = atomicAdd(&cnt2[d], 1);
        if (s < CAP) eidx2[(size_t)d * CAP + s] = src2[i];
    }
}

// One wave per node: gather fp32 rows (8-deep unroll, idx prefetch), mean,
// write bf16 row.
__global__ __launch_bounds__(256) void csr_mean_f32b16(const float* __restrict__ feat,
                                                       const int* __restrict__ eidx,
                                                       const int* __restrict__ cnt, int M,
                                                       unsigned short* __restrict__ outMean) {
    int node = blockIdx.x * 4 + (threadIdx.x >> 6);
    if (node >= M) return;
    int lane = threadIdx.x & 63;
    const int* slots = eidx + (size_t)node * CAP;
    int deg = min(cnt[node], CAP);
    float ax = 0.f, ay = 0.f, az = 0.f, aw = 0.f;
    int j = 0;
    if (j + 8 <= deg) {
        int s[8];
        #pragma unroll
        for (int u = 0; u < 8; ++u) s[u] = slots[u];
        for (;;) {
            float4 v[8];
            #pragma unroll
            for (int u = 0; u < 8; ++u)
                v[u] = ((const float4*)(feat + (size_t)s[u] * DIM))[lane];
            j += 8;
            bool more = (j + 8 <= deg);
            if (more) {
                #pragma unroll
                for (int u = 0; u < 8; ++u) s[u] = slots[j + u];
            }
            #pragma unroll
            for (int u = 0; u < 8; ++u) {
                ax += v[u].x; ay += v[u].y; az += v[u].z; aw += v[u].w;
            }
            if (!more) break;
        }
    }
    for (; j + 4 <= deg; j += 4) {
        int s0 = slots[j], s1 = slots[j + 1], s2 = slots[j + 2], s3 = slots[j + 3];
        float4 v0 = ((const float4*)(feat + (size_t)s0 * DIM))[lane];
        float4 v1 = ((const float4*)(feat + (size_t)s1 * DIM))[lane];
        float4 v2 = ((const float4*)(feat + (size_t)s2 * DIM))[lane];
        float4 v3 = ((const float4*)(feat + (size_t)s3 * DIM))[lane];
        ax += (v0.x + v1.x) + (v2.x + v3.x);
        ay += (v0.y + v1.y) + (v2.y + v3.y);
        az += (v0.z + v1.z) + (v2.z + v3.z);
        aw += (v0.w + v1.w) + (v2.w + v3.w);
    }
    for (; j < deg; ++j) {
        float4 v0 = ((const float4*)(feat + (size_t)slots[j] * DIM))[lane];
        ax += v0.x; ay += v0.y; az += v0.z; aw += v0.w;
    }
    float sc = deg > 0 ? 1.0f / (float)deg : 0.0f;
    ushort4 r;
    r.x = f2b(ax * sc); r.y = f2b(ay * sc); r.z = f2b(az * sc); r.w = f2b(aw * sc);
    ((ushort4*)(outMean + (size_t)node * DIM))[lane] = r;
}

// One wave per node: gather bf16 rows, mean, write bf16 row (layer 2: small).
__global__ __launch_bounds__(256) void csr_mean_b16b16(const unsigned short* __restrict__ feat,
                                                       const int* __restrict__ eidx,
                                                       const int* __restrict__ cnt, int M,
                                                       unsigned short* __restrict__ outMean) {
    int node = blockIdx.x * 4 + (threadIdx.x >> 6);
    if (node >= M) return;
    int lane = threadIdx.x & 63;
    const int* slots = eidx + (size_t)node * CAP;
    int deg = min(cnt[node], CAP);
    float ax = 0.f, ay = 0.f, az = 0.f, aw = 0.f;
    int j = 0;
    for (; j + 2 <= deg; j += 2) {
        int s0 = slots[j], s1 = slots[j + 1];
        ushort4 v0 = ((const ushort4*)(feat + (size_t)s0 * DIM))[lane];
        ushort4 v1 = ((const ushort4*)(feat + (size_t)s1 * DIM))[lane];
        ax += b2f(v0.x) + b2f(v1.x); ay += b2f(v0.y) + b2f(v1.y);
        az += b2f(v0.z) + b2f(v1.z); aw += b2f(v0.w) + b2f(v1.w);
    }
    if (j < deg) {
        ushort4 v0 = ((const ushort4*)(feat + (size_t)slots[j] * DIM))[lane];
        ax += b2f(v0.x); ay += b2f(v0.y); az += b2f(v0.z); aw += b2f(v0.w);
    }
    float sc = deg > 0 ? 1.0f / (float)deg : 0.0f;
    ushort4 r;
    r.x = f2b(ax * sc); r.y = f2b(ay * sc); r.z = f2b(az * sc); r.w = f2b(aw * sc);
    ((ushort4*)(outMean + (size_t)node * DIM))[lane] = r;
}

// out = relu(mean @ Wl + self @ Wr + bl). Block = 128 rows x 64 cols: 8 waves
// SPLIT ROWS (16 each) and SHARE the same 4 col-tiles. grid = (M/128, 4),
// 512 threads. Per-wave work identical to the proven row-split kernel; B
// L2-traffic halves vs 64-row blocks.
template <int SELF_F32, int OUT_BF16>
__global__ __launch_bounds__(512) void gemm_rs(const unsigned short* __restrict__ meanb,
                                               const void* __restrict__ selfv,
                                               const unsigned short* __restrict__ PWl,
                                               const unsigned short* __restrict__ PWr,
                                               const float* __restrict__ bl,
                                               void* __restrict__ out, int M) {
    int t = threadIdx.x, lane = t & 63, wid = t >> 6;
    int blockRow = blockIdx.x * 128 + wid * 16;  // wave's 16 rows
    int ntBase = blockIdx.y * 4;                 // 4 col-tiles shared by all waves
    int rowA = blockRow + (lane & 15);
    int sarow = rowA < M ? rowA : (M - 1);
    int koff = (lane >> 4) * 8;

    short8v a_mean[8], a_self[8];
    {
        const unsigned short* mp = meanb + (size_t)sarow * 256 + koff;
        #pragma unroll
        for (int kt = 0; kt < 8; ++kt) a_mean[kt] = *(const short8v*)(mp + kt * 32);
    }
    if (SELF_F32) {
        const float* sp = (const float*)selfv + (size_t)sarow * 256 + koff;
        #pragma unroll
        for (int kt = 0; kt < 8; ++kt) {
            float4 f0 = *(const float4*)(sp + kt * 32);
            float4 f1 = *(const float4*)(sp + kt * 32 + 4);
            short8v s;
            s[0] = f2b(f0.x); s[1] = f2b(f0.y); s[2] = f2b(f0.z); s[3] = f2b(f0.w);
            s[4] = f2b(f1.x); s[5] = f2b(f1.y); s[6] = f2b(f1.z); s[7] = f2b(f1.w);
            a_self[kt] = s;
        }
    } else {
        const unsigned short* sp = (const unsigned short*)selfv + (size_t)sarow * 256 + koff;
        #pragma unroll
        for (int kt = 0; kt < 8; ++kt) a_self[kt] = *(const short8v*)(sp + kt * 32);
    }

    int ocol16 = lane & 15;
    int orow0 = blockRow + (lane >> 4) * 4;

    #pragma unroll
    for (int q = 0; q < 4; ++q) {
        int nt = ntBase + q;
        const unsigned short* bpl = PWl + (size_t)nt * 4096 + lane * 8;
        const unsigned short* bpr = PWr + (size_t)nt * 4096 + lane * 8;
        f32x4 acc = {};
        #pragma unroll
        for (int kt = 0; kt < 8; ++kt) {
            short8v b = *(const short8v*)(bpl + kt * 512);
            acc = __builtin_amdgcn_mfma_f32_16x16x32_bf16(a_mean[kt], b, acc, 0, 0, 0);
        }
        #pragma unroll
        for (int kt = 0; kt < 8; ++kt) {
            short8v b = *(const short8v*)(bpr + kt * 512);
            acc = __builtin_amdgcn_mfma_f32_16x16x32_bf16(a_self[kt], b, acc, 0, 0, 0);
        }
        int col = nt * 16 + ocol16;
        float bias = bl[col];
        #pragma unroll
        for (int r = 0; r < 4; ++r) {
            int row = orow0 + r;
            if (row < M) {
                float v = fmaxf(acc[r] + bias, 0.0f);
                if (OUT_BF16) ((unsigned short*)out)[(size_t)row * 256 + col] = f2b(v);
                else          ((float*)out)[(size_t)row * 256 + col] = v;
            }
        }
    }
}

// One wave per link: out[l] = h2[inv[a]].Wlin[0:256] + h2[inv[b]].Wlin[256:512] + blin
__global__ __launch_bounds__(256) void link_pred(const float* __restrict__ h2,
                                                 const int* __restrict__ link,
                                                 const int* __restrict__ inv,
                                                 const float* __restrict__ Wlin,
                                                 const float* __restrict__ blin,
                                                 float* __restrict__ out, int L) {
    int l = blockIdx.x * 4 + (threadIdx.x >> 6);
    if (l >= L) return;
    int lane = threadIdx.x & 63;
    int a = inv[link[2 * l + 0]];
    int b = inv[link[2 * l + 1]];
    float4 ha = ((const float4*)(h2 + (size_t)a * DIM))[lane];
    float4 hb = ((const float4*)(h2 + (size_t)b * DIM))[lane];
    float4 wa = ((const float4*)(Wlin))[lane];
    float4 wb = ((const float4*)(Wlin + DIM))[lane];
    float p = ha.x * wa.x + ha.y * wa.y + ha.z * wa.z + ha.w * wa.w
            + hb.x * wb.x + hb.y * wb.y + hb.z * wb.z + hb.w * wb.w;
    #pragma unroll
    for (int off = 32; off; off >>= 1) p += __shfl_down(p, off, 64);
    if (lane == 0) out[l] = p + blin[0];
}

extern "C" void kernel_launch(void* const* d_in, const int* in_sizes, int n_in,
                              void* d_out, int out_size, void* d_ws, size_t ws_size,
                              hipStream_t stream) {
    const float* x    = (const float*)d_in[0];
    const int*   src1 = (const int*)d_in[1];
    const int*   dst1 = (const int*)d_in[2];
    const int*   src2 = (const int*)d_in[3];
    const int*   dst2 = (const int*)d_in[4];
    const int*   link = (const int*)d_in[7];
    const int*   n_id = (const int*)d_in[8];
    const float* Wl1  = (const float*)d_in[9];
    const float* bl1  = (const float*)d_in[10];
    const float* Wr1  = (const float*)d_in[11];
    const float* Wl2  = (const float*)d_in[12];
    const float* bl2  = (const float*)d_in[13];
    const float* Wr2  = (const float*)d_in[14];
    const float* Wlin = (const float*)d_in[15];
    const float* blin = (const float*)d_in[16];

    const int N0 = in_sizes[0] / DIM;   // 400000
    const int E1 = in_sizes[1];         // 400000
    const int E2 = in_sizes[3];         // 40000
    const int L  = in_sizes[7] / 2;     // 4096
    const int N1 = 40000;
    const int N2 = 4000;

    char* p = (char*)d_ws;
    auto alloc = [&](size_t bytes) { char* r = p; p += (bytes + 255) & ~(size_t)255; return r; };

    unsigned short* meanb1 = (unsigned short*)alloc((size_t)N1 * DIM * 2);
    unsigned short* h1b    = (unsigned short*)alloc((size_t)N1 * DIM * 2);
    unsigned short* meanb2 = (unsigned short*)alloc((size_t)N2 * DIM * 2);
    float*          h2     = (float*)alloc((size_t)N2 * DIM * 4);
    unsigned short* PWl1   = (unsigned short*)alloc(256 * 256 * 2);
    unsigned short* PWr1   = (unsigned short*)alloc(256 * 256 * 2);
    unsigned short* PWl2   = (unsigned short*)alloc(256 * 256 * 2);
    unsigned short* PWr2   = (unsigned short*)alloc(256 * 256 * 2);
    int* inv   = (int*)alloc((size_t)N0 * 4);
    int* eidx1 = (int*)alloc((size_t)N1 * CAP * 4);
    int* eidx2 = (int*)alloc((size_t)N2 * CAP * 4);
    int* cnt1  = (int*)alloc((size_t)(N1 + N2) * 4);   // contiguous: zeroed in pack_zero
    int* cnt2  = cnt1 + N1;

    pack_zero<<<dim3(16, 8, 4), 64, 0, stream>>>(Wl1, Wr1, Wl2, Wr2, PWl1, PWr1, PWl2, PWr2,
                                                 cnt1, N1 + N2);
    scatter_all<<<(N0 + 255) / 256, 256, 0, stream>>>(n_id, inv, N0,
                                                      src1, dst1, E1, cnt1, eidx1,
                                                      src2, dst2, E2, cnt2, eidx2);

    csr_mean_f32b16<<<(N1 + 3) / 4, 256, 0, stream>>>(x, eidx1, cnt1, N1, meanb1);
    gemm_rs<1, 1><<<dim3((N1 + 127) / 128, 4), 512, 0, stream>>>(meanb1, x, PWl1, PWr1, bl1, h1b, N1);

    csr_mean_b16b16<<<(N2 + 3) / 4, 256, 0, stream>>>(h1b, eidx2, cnt2, N2, meanb2);
    gemm_rs<0, 0><<<dim3((N2 + 127) / 128, 4), 512, 0, stream>>>(meanb2, h1b, PWl2, PWr2, bl2, h2, N2);

    link_pred<<<(L + 3) / 4, 256, 0, stream>>>(h2, link, inv, Wlin, blin, (float*)d_out, L);
}

// Round 11
// 179.690 us; speedup vs baseline: 1.1083x; 1.1083x over previous
//
#include <hip/hip_runtime.h>

// GraphSAGE forward: 2x SAGEConv(mean) + ReLU, then link scorer. D = H = 256.
// Bucket-slot edge lists (no scan) -> wide-parallel gather-mean -> MFMA GEMM.
// == Round-9 configuration (best: 179.8 us). gemm: 64 rows/block, 4 waves
// row-split sharing 4 col-tiles, 256-thread blocks, grid (M/64, 4).

#define DIM 256
#define CAP 64   // max degree capacity per node (Poisson(10): P(>64) ~ 1e-31)
typedef __attribute__((ext_vector_type(8))) short short8v;
typedef __attribute__((ext_vector_type(4))) float f32x4;

__device__ inline unsigned short f2b(float f) {
    unsigned u = __builtin_bit_cast(unsigned, f);
    unsigned r = 0x7FFFu + ((u >> 16) & 1u);
    return (unsigned short)((u + r) >> 16);
}
__device__ inline float b2f(unsigned short h) {
    unsigned u = ((unsigned)h) << 16;
    return __builtin_bit_cast(float, u);
}

// Pack 256x256 f32 row-major weights into bf16 MFMA B-fragment order, and zero
// the degree-count arrays (no separate memset dispatch).
// P[((nt*8+kt)*64+lane)*8+j] = bf16(W[kt*32 + 8*(lane>>4)+j][nt*16 + (lane&15)])
__global__ __launch_bounds__(64) void pack_zero(const float* __restrict__ W0, const float* __restrict__ W1,
                                                const float* __restrict__ W2, const float* __restrict__ W3,
                                                unsigned short* __restrict__ P0, unsigned short* __restrict__ P1,
                                                unsigned short* __restrict__ P2, unsigned short* __restrict__ P3,
                                                int* __restrict__ cntz, int nz) {
    const float* W; unsigned short* P;
    switch (blockIdx.z) {
        case 0: W = W0; P = P0; break;
        case 1: W = W1; P = P1; break;
        case 2: W = W2; P = P2; break;
        default: W = W3; P = P3; break;
    }
    int nt = blockIdx.x, kt = blockIdx.y, lane = threadIdx.x;
    int r = kt * 32 + ((lane >> 4) * 8);
    int c = nt * 16 + (lane & 15);
    short8v v;
    #pragma unroll
    for (int j = 0; j < 8; ++j) v[j] = f2b(W[(size_t)(r + j) * 256 + c]);
    *(short8v*)(P + ((size_t)(nt * 8 + kt) * 64 + lane) * 8) = v;
    int tid = ((blockIdx.z * gridDim.y + blockIdx.y) * gridDim.x + blockIdx.x) * 64 + lane;
    for (int i = tid; i < nz; i += 32768) cntz[i] = 0;
}

// inv scatter + bucket-slot scatter for both layers (cnt arrays pre-zeroed).
__global__ __launch_bounds__(256) void scatter_all(const int* __restrict__ n_id, int* __restrict__ inv, int n0,
                                                   const int* __restrict__ src1, const int* __restrict__ dst1, int E1,
                                                   int* __restrict__ cnt1, int* __restrict__ eidx1,
                                                   const int* __restrict__ src2, const int* __restrict__ dst2, int E2,
                                                   int* __restrict__ cnt2, int* __restrict__ eidx2) {
    int i = blockIdx.x * blockDim.x + threadIdx.x;
    if (i < n0) inv[n_id[i]] = i;
    if (i < E1) {
        int d = dst1[i];
        int s = atomicAdd(&cnt1[d], 1);
        if (s < CAP) eidx1[(size_t)d * CAP + s] = src1[i];
    }
    if (i < E2) {
        int d = dst2[i];
        int s = atomicAdd(&cnt2[d], 1);
        if (s < CAP) eidx2[(size_t)d * CAP + s] = src2[i];
    }
}

// One wave per node: gather fp32 rows (8-deep unroll, idx prefetch), mean,
// write bf16 row.
__global__ __launch_bounds__(256) void csr_mean_f32b16(const float* __restrict__ feat,
                                                       const int* __restrict__ eidx,
                                                       const int* __restrict__ cnt, int M,
                                                       unsigned short* __restrict__ outMean) {
    int node = blockIdx.x * 4 + (threadIdx.x >> 6);
    if (node >= M) return;
    int lane = threadIdx.x & 63;
    const int* slots = eidx + (size_t)node * CAP;
    int deg = min(cnt[node], CAP);
    float ax = 0.f, ay = 0.f, az = 0.f, aw = 0.f;
    int j = 0;
    if (j + 8 <= deg) {
        int s[8];
        #pragma unroll
        for (int u = 0; u < 8; ++u) s[u] = slots[u];
        for (;;) {
            float4 v[8];
            #pragma unroll
            for (int u = 0; u < 8; ++u)
                v[u] = ((const float4*)(feat + (size_t)s[u] * DIM))[lane];
            j += 8;
            bool more = (j + 8 <= deg);
            if (more) {
                #pragma unroll
                for (int u = 0; u < 8; ++u) s[u] = slots[j + u];
            }
            #pragma unroll
            for (int u = 0; u < 8; ++u) {
                ax += v[u].x; ay += v[u].y; az += v[u].z; aw += v[u].w;
            }
            if (!more) break;
        }
    }
    for (; j + 4 <= deg; j += 4) {
        int s0 = slots[j], s1 = slots[j + 1], s2 = slots[j + 2], s3 = slots[j + 3];
        float4 v0 = ((const float4*)(feat + (size_t)s0 * DIM))[lane];
        float4 v1 = ((const float4*)(feat + (size_t)s1 * DIM))[lane];
        float4 v2 = ((const float4*)(feat + (size_t)s2 * DIM))[lane];
        float4 v3 = ((const float4*)(feat + (size_t)s3 * DIM))[lane];
        ax += (v0.x + v1.x) + (v2.x + v3.x);
        ay += (v0.y + v1.y) + (v2.y + v3.y);
        az += (v0.z + v1.z) + (v2.z + v3.z);
        aw += (v0.w + v1.w) + (v2.w + v3.w);
    }
    for (; j < deg; ++j) {
        float4 v0 = ((const float4*)(feat + (size_t)slots[j] * DIM))[lane];
        ax += v0.x; ay += v0.y; az += v0.z; aw += v0.w;
    }
    float sc = deg > 0 ? 1.0f / (float)deg : 0.0f;
    ushort4 r;
    r.x = f2b(ax * sc); r.y = f2b(ay * sc); r.z = f2b(az * sc); r.w = f2b(aw * sc);
    ((ushort4*)(outMean + (size_t)node * DIM))[lane] = r;
}

// One wave per node: gather bf16 rows, mean, write bf16 row (layer 2: small).
__global__ __launch_bounds__(256) void csr_mean_b16b16(const unsigned short* __restrict__ feat,
                                                       const int* __restrict__ eidx,
                                                       const int* __restrict__ cnt, int M,
                                                       unsigned short* __restrict__ outMean) {
    int node = blockIdx.x * 4 + (threadIdx.x >> 6);
    if (node >= M) return;
    int lane = threadIdx.x & 63;
    const int* slots = eidx + (size_t)node * CAP;
    int deg = min(cnt[node], CAP);
    float ax = 0.f, ay = 0.f, az = 0.f, aw = 0.f;
    int j = 0;
    for (; j + 2 <= deg; j += 2) {
        int s0 = slots[j], s1 = slots[j + 1];
        ushort4 v0 = ((const ushort4*)(feat + (size_t)s0 * DIM))[lane];
        ushort4 v1 = ((const ushort4*)(feat + (size_t)s1 * DIM))[lane];
        ax += b2f(v0.x) + b2f(v1.x); ay += b2f(v0.y) + b2f(v1.y);
        az += b2f(v0.z) + b2f(v1.z); aw += b2f(v0.w) + b2f(v1.w);
    }
    if (j < deg) {
        ushort4 v0 = ((const ushort4*)(feat + (size_t)slots[j] * DIM))[lane];
        ax += b2f(v0.x); ay += b2f(v0.y); az += b2f(v0.z); aw += b2f(v0.w);
    }
    float sc = deg > 0 ? 1.0f / (float)deg : 0.0f;
    ushort4 r;
    r.x = f2b(ax * sc); r.y = f2b(ay * sc); r.z = f2b(az * sc); r.w = f2b(aw * sc);
    ((ushort4*)(outMean + (size_t)node * DIM))[lane] = r;
}

// out = relu(mean @ Wl + self @ Wr + bl). Block = 64 rows x 64 cols: 4 waves
// SPLIT ROWS (16 each) and SHARE the same 4 col-tiles (B L1-dedup'd).
// grid = (M/64, 4), 256 threads. [R10 lesson: keep workgroups small — 512-thr
// blocks at equal wave count regressed 19 us.]
template <int SELF_F32, int OUT_BF16>
__global__ __launch_bounds__(256) void gemm_rs(const unsigned short* __restrict__ meanb,
                                               const void* __restrict__ selfv,
                                               const unsigned short* __restrict__ PWl,
                                               const unsigned short* __restrict__ PWr,
                                               const float* __restrict__ bl,
                                               void* __restrict__ out, int M) {
    int t = threadIdx.x, lane = t & 63, wid = t >> 6;
    int blockRow = blockIdx.x * 64 + wid * 16;   // wave's 16 rows
    int ntBase = blockIdx.y * 4;                 // 4 col-tiles shared by all waves
    int rowA = blockRow + (lane & 15);
    int sarow = rowA < M ? rowA : (M - 1);
    int koff = (lane >> 4) * 8;

    short8v a_mean[8], a_self[8];
    {
        const unsigned short* mp = meanb + (size_t)sarow * 256 + koff;
        #pragma unroll
        for (int kt = 0; kt < 8; ++kt) a_mean[kt] = *(const short8v*)(mp + kt * 32);
    }
    if (SELF_F32) {
        const float* sp = (const float*)selfv + (size_t)sarow * 256 + koff;
        #pragma unroll
        for (int kt = 0; kt < 8; ++kt) {
            float4 f0 = *(const float4*)(sp + kt * 32);
            float4 f1 = *(const float4*)(sp + kt * 32 + 4);
            short8v s;
            s[0] = f2b(f0.x); s[1] = f2b(f0.y); s[2] = f2b(f0.z); s[3] = f2b(f0.w);
            s[4] = f2b(f1.x); s[5] = f2b(f1.y); s[6] = f2b(f1.z); s[7] = f2b(f1.w);
            a_self[kt] = s;
        }
    } else {
        const unsigned short* sp = (const unsigned short*)selfv + (size_t)sarow * 256 + koff;
        #pragma unroll
        for (int kt = 0; kt < 8; ++kt) a_self[kt] = *(const short8v*)(sp + kt * 32);
    }

    int ocol16 = lane & 15;
    int orow0 = blockRow + (lane >> 4) * 4;

    #pragma unroll
    for (int q = 0; q < 4; ++q) {
        int nt = ntBase + q;
        const unsigned short* bpl = PWl + (size_t)nt * 4096 + lane * 8;
        const unsigned short* bpr = PWr + (size_t)nt * 4096 + lane * 8;
        f32x4 acc = {};
        #pragma unroll
        for (int kt = 0; kt < 8; ++kt) {
            short8v b = *(const short8v*)(bpl + kt * 512);
            acc = __builtin_amdgcn_mfma_f32_16x16x32_bf16(a_mean[kt], b, acc, 0, 0, 0);
        }
        #pragma unroll
        for (int kt = 0; kt < 8; ++kt) {
            short8v b = *(const short8v*)(bpr + kt * 512);
            acc = __builtin_amdgcn_mfma_f32_16x16x32_bf16(a_self[kt], b, acc, 0, 0, 0);
        }
        int col = nt * 16 + ocol16;
        float bias = bl[col];
        #pragma unroll
        for (int r = 0; r < 4; ++r) {
            int row = orow0 + r;
            if (row < M) {
                float v = fmaxf(acc[r] + bias, 0.0f);
                if (OUT_BF16) ((unsigned short*)out)[(size_t)row * 256 + col] = f2b(v);
                else          ((float*)out)[(size_t)row * 256 + col] = v;
            }
        }
    }
}

// One wave per link: out[l] = h2[inv[a]].Wlin[0:256] + h2[inv[b]].Wlin[256:512] + blin
__global__ __launch_bounds__(256) void link_pred(const float* __restrict__ h2,
                                                 const int* __restrict__ link,
                                                 const int* __restrict__ inv,
                                                 const float* __restrict__ Wlin,
                                                 const float* __restrict__ blin,
                                                 float* __restrict__ out, int L) {
    int l = blockIdx.x * 4 + (threadIdx.x >> 6);
    if (l >= L) return;
    int lane = threadIdx.x & 63;
    int a = inv[link[2 * l + 0]];
    int b = inv[link[2 * l + 1]];
    float4 ha = ((const float4*)(h2 + (size_t)a * DIM))[lane];
    float4 hb = ((const float4*)(h2 + (size_t)b * DIM))[lane];
    float4 wa = ((const float4*)(Wlin))[lane];
    float4 wb = ((const float4*)(Wlin + DIM))[lane];
    float p = ha.x * wa.x + ha.y * wa.y + ha.z * wa.z + ha.w * wa.w
            + hb.x * wb.x + hb.y * wb.y + hb.z * wb.z + hb.w * wb.w;
    #pragma unroll
    for (int off = 32; off; off >>= 1) p += __shfl_down(p, off, 64);
    if (lane == 0) out[l] = p + blin[0];
}

extern "C" void kernel_launch(void* const* d_in, const int* in_sizes, int n_in,
                              void* d_out, int out_size, void* d_ws, size_t ws_size,
                              hipStream_t stream) {
    const float* x    = (const float*)d_in[0];
    const int*   src1 = (const int*)d_in[1];
    const int*   dst1 = (const int*)d_in[2];
    const int*   src2 = (const int*)d_in[3];
    const int*   dst2 = (const int*)d_in[4];
    const int*   link = (const int*)d_in[7];
    const int*   n_id = (const int*)d_in[8];
    const float* Wl1  = (const float*)d_in[9];
    const float* bl1  = (const float*)d_in[10];
    const float* Wr1  = (const float*)d_in[11];
    const float* Wl2  = (const float*)d_in[12];
    const float* bl2  = (const float*)d_in[13];
    const float* Wr2  = (const float*)d_in[14];
    const float* Wlin = (const float*)d_in[15];
    const float* blin = (const float*)d_in[16];

    const int N0 = in_sizes[0] / DIM;   // 400000
    const int E1 = in_sizes[1];         // 400000
    const int E2 = in_sizes[3];         // 40000
    const int L  = in_sizes[7] / 2;     // 4096
    const int N1 = 40000;
    const int N2 = 4000;

    char* p = (char*)d_ws;
    auto alloc = [&](size_t bytes) { char* r = p; p += (bytes + 255) & ~(size_t)255; return r; };

    unsigned short* meanb1 = (unsigned short*)alloc((size_t)N1 * DIM * 2);
    unsigned short* h1b    = (unsigned short*)alloc((size_t)N1 * DIM * 2);
    unsigned short* meanb2 = (unsigned short*)alloc((size_t)N2 * DIM * 2);
    float*          h2     = (float*)alloc((size_t)N2 * DIM * 4);
    unsigned short* PWl1   = (unsigned short*)alloc(256 * 256 * 2);
    unsigned short* PWr1   = (unsigned short*)alloc(256 * 256 * 2);
    unsigned short* PWl2   = (unsigned short*)alloc(256 * 256 * 2);
    unsigned short* PWr2   = (unsigned short*)alloc(256 * 256 * 2);
    int* inv   = (int*)alloc((size_t)N0 * 4);
    int* eidx1 = (int*)alloc((size_t)N1 * CAP * 4);
    int* eidx2 = (int*)alloc((size_t)N2 * CAP * 4);
    int* cnt1  = (int*)alloc((size_t)(N1 + N2) * 4);   // contiguous: zeroed in pack_zero
    int* cnt2  = cnt1 + N1;

    pack_zero<<<dim3(16, 8, 4), 64, 0, stream>>>(Wl1, Wr1, Wl2, Wr2, PWl1, PWr1, PWl2, PWr2,
                                                 cnt1, N1 + N2);
    scatter_all<<<(N0 + 255) / 256, 256, 0, stream>>>(n_id, inv, N0,
                                                      src1, dst1, E1, cnt1, eidx1,
                                                      src2, dst2, E2, cnt2, eidx2);

    csr_mean_f32b16<<<(N1 + 3) / 4, 256, 0, stream>>>(x, eidx1, cnt1, N1, meanb1);
    gemm_rs<1, 1><<<dim3((N1 + 63) / 64, 4), 256, 0, stream>>>(meanb1, x, PWl1, PWr1, bl1, h1b, N1);

    csr_mean_b16b16<<<(N2 + 3) / 4, 256, 0, stream>>>(h1b, eidx2, cnt2, N2, meanb2);
    gemm_rs<0, 0><<<dim3((N2 + 63) / 64, 4), 256, 0, stream>>>(meanb2, h1b, PWl2, PWr2, bl2, h2, N2);

    link_pred<<<(L + 3) / 4, 256, 0, stream>>>(h2, link, inv, Wlin, blin, (float*)d_out, L);
}